// Round 1
// baseline (2719.281 us; speedup 1.0000x reference)
//
#include <hip/hip_runtime.h>

#define NN 20000
#define NE 320000
#define NG 64
#define D 128
#define D3 384
#define NRBF 20
#define PI_F 3.14159265358979323846f
#define RCUT 10.0f

__device__ __forceinline__ float silu_f(float x) {
    return x / (1.0f + __expf(-x));
}

// ---------------------------------------------------------------- init
// s = embedding[atom_types]; v = 0; g = 0
__global__ __launch_bounds__(256) void init_all(
    const int* __restrict__ atype, const float* __restrict__ emb,
    float* __restrict__ s, float* __restrict__ v, float* __restrict__ g)
{
    int idx = blockIdx.x * blockDim.x + threadIdx.x;
    if (idx < NN * D) {
        int n = idx >> 7, d = idx & 127;
        s[idx] = emb[atype[n] * D + d];
    }
    if (idx < NG * D) g[idx] = 0.0f;
    for (int i = idx; i < NN * 3 * D; i += gridDim.x * blockDim.x) v[i] = 0.0f;
}

// ---------------------------------------------------------------- edge geometry
// rbfs[e][k] = sin((k+1)*pi*r/RCUT)/r * fcut ; fcut[e]; dirs = vec/r
__global__ __launch_bounds__(256) void edge_geom(
    const float* __restrict__ evec,
    float* __restrict__ rbfs, float* __restrict__ fcutb, float* __restrict__ dirs)
{
    int e = blockIdx.x * blockDim.x + threadIdx.x;
    if (e >= NE) return;
    float x = evec[e * 3 + 0], y = evec[e * 3 + 1], z = evec[e * 3 + 2];
    float r = sqrtf(x * x + y * y + z * z);
    float inv = 1.0f / r;
    dirs[e * 3 + 0] = x * inv;
    dirs[e * 3 + 1] = y * inv;
    dirs[e * 3 + 2] = z * inv;
    float f = (r < RCUT) ? 0.5f * (cosf(PI_F * r / RCUT) + 1.0f) : 0.0f;
    fcutb[e] = f;
    float base = PI_F * r / RCUT;
    float sf = inv * f;
    #pragma unroll
    for (int k = 0; k < NRBF; k++) {
        rbfs[e * NRBF + k] = sinf((float)(k + 1) * base) * sf;
    }
}

// ---------------------------------------------------------------- phi MLP (per node)
// phi = silu(s @ w1 + b1) @ w2 + b2   — 8 rows per 256-thread block
__global__ __launch_bounds__(256) void phi_mlp(
    const float* __restrict__ s,
    const float* __restrict__ w1, const float* __restrict__ b1,
    const float* __restrict__ w2, const float* __restrict__ b2,
    float* __restrict__ phi)
{
    __shared__ float sl[8][D];
    __shared__ float hl[8][D];
    int j = threadIdx.x & 127;
    int half = threadIdx.x >> 7;
    int n0 = blockIdx.x * 8;
    for (int t = threadIdx.x; t < 8 * D; t += 256)
        sl[t >> 7][t & 127] = s[n0 * D + t];
    __syncthreads();
    float acc[4];
    #pragma unroll
    for (int q = 0; q < 4; q++) acc[q] = b1[j];
    for (int k = 0; k < D; k++) {
        float w = w1[k * D + j];
        #pragma unroll
        for (int q = 0; q < 4; q++) acc[q] += sl[half * 4 + q][k] * w;
    }
    #pragma unroll
    for (int q = 0; q < 4; q++) hl[half * 4 + q][j] = silu_f(acc[q]);
    __syncthreads();
    float a0[4], a1[4], a2[4];
    #pragma unroll
    for (int q = 0; q < 4; q++) { a0[q] = b2[j]; a1[q] = b2[D + j]; a2[q] = b2[2 * D + j]; }
    for (int k = 0; k < D; k++) {
        float wa = w2[k * D3 + j];
        float wb = w2[k * D3 + D + j];
        float wc = w2[k * D3 + 2 * D + j];
        #pragma unroll
        for (int q = 0; q < 4; q++) {
            float h = hl[half * 4 + q][k];
            a0[q] += h * wa; a1[q] += h * wb; a2[q] += h * wc;
        }
    }
    #pragma unroll
    for (int q = 0; q < 4; q++) {
        int n = n0 + half * 4 + q;
        phi[n * D3 + j]         = a0[q];
        phi[n * D3 + D + j]     = a1[q];
        phi[n * D3 + 2 * D + j] = a2[q];
    }
}

// ---------------------------------------------------------------- copy s,v -> s',v'
__global__ __launch_bounds__(256) void copy_sv(
    const float4* __restrict__ s_src, float4* __restrict__ s_dst,
    const float4* __restrict__ v_src, float4* __restrict__ v_dst)
{
    int idx = blockIdx.x * blockDim.x + threadIdx.x;
    const int ns4 = NN * D / 4;
    if (idx < ns4) s_dst[idx] = s_src[idx];
    const int nv4 = NN * 3 * D / 4;
    for (int i = idx; i < nv4; i += gridDim.x * blockDim.x) v_dst[i] = v_src[i];
}

// ---------------------------------------------------------------- edge message
// one wave (64 lanes) per edge; each lane owns channel pair d = lane*2 within [0,128)
__global__ __launch_bounds__(256) void edge_msg(
    const int* __restrict__ src, const int* __restrict__ dst,
    const float* __restrict__ phi, const float* __restrict__ v_old,
    const float* __restrict__ rbfs, const float* __restrict__ fcutb,
    const float* __restrict__ dirs,
    const float* __restrict__ filt_w, const float* __restrict__ filt_b,
    float* __restrict__ s_new, float* __restrict__ v_new)
{
    int e = (blockIdx.x * blockDim.x + threadIdx.x) >> 6;
    if (e >= NE) return;
    int lane = threadIdx.x & 63;
    int sn = src[e], dn = dst[e];
    float fc = fcutb[e];
    int d = lane * 2;

    float2 fb0 = *(const float2*)&filt_b[d];
    float2 fb1 = *(const float2*)&filt_b[D + d];
    float2 fb2 = *(const float2*)&filt_b[2 * D + d];
    float W0x = fc * fb0.x, W0y = fc * fb0.y;
    float W1x = fc * fb1.x, W1y = fc * fb1.y;
    float W2x = fc * fb2.x, W2y = fc * fb2.y;
    #pragma unroll
    for (int k = 0; k < NRBF; k++) {
        float rb = rbfs[e * NRBF + k];
        float2 w0 = *(const float2*)&filt_w[k * D3 + d];
        float2 w1 = *(const float2*)&filt_w[k * D3 + D + d];
        float2 w2 = *(const float2*)&filt_w[k * D3 + 2 * D + d];
        W0x += rb * w0.x; W0y += rb * w0.y;
        W1x += rb * w1.x; W1y += rb * w1.y;
        W2x += rb * w2.x; W2y += rb * w2.y;
    }

    float2 p0 = *(const float2*)&phi[sn * D3 + d];
    float2 p1 = *(const float2*)&phi[sn * D3 + D + d];
    float2 p2 = *(const float2*)&phi[sn * D3 + 2 * D + d];
    float m1x = p0.x * W0x, m1y = p0.y * W0y;
    float m2x = p1.x * W1x, m2y = p1.y * W1y;
    float m3x = p2.x * W2x, m3y = p2.y * W2y;

    atomicAdd(&s_new[dn * D + d],     m2x);
    atomicAdd(&s_new[dn * D + d + 1], m2y);

    float dir0 = dirs[e * 3 + 0], dir1 = dirs[e * 3 + 1], dir2 = dirs[e * 3 + 2];
    float dir[3] = {dir0, dir1, dir2};
    #pragma unroll
    for (int i = 0; i < 3; i++) {
        float2 vv = *(const float2*)&v_old[(sn * 3 + i) * D + d];
        atomicAdd(&v_new[(dn * 3 + i) * D + d],     vv.x * m1x + dir[i] * m3x);
        atomicAdd(&v_new[(dn * 3 + i) * D + d + 1], vv.y * m1y + dir[i] * m3y);
    }
}

// ---------------------------------------------------------------- U/Vp/UV/Vn (per node)
// 4 nodes per 256-thread block; each thread handles 2 nodes
__global__ __launch_bounds__(256) void node_uv(
    const float* __restrict__ v,
    const float* __restrict__ Uw, const float* __restrict__ Vw,
    float* __restrict__ U, float* __restrict__ UV, float* __restrict__ Vn)
{
    __shared__ float vl[4][3][D];
    int j = threadIdx.x & 127;
    int half = threadIdx.x >> 7;
    int n0 = blockIdx.x * 4;
    for (int t = threadIdx.x; t < 4 * 3 * D; t += 256)
        vl[t / 384][(t / 128) % 3][t & 127] = v[n0 * 384 + t];
    __syncthreads();
    float u[2][3] = {{0,0,0},{0,0,0}};
    float p[2][3] = {{0,0,0},{0,0,0}};
    for (int k = 0; k < D; k++) {
        float wu = Uw[k * D + j], wv = Vw[k * D + j];
        #pragma unroll
        for (int q = 0; q < 2; q++)
            #pragma unroll
            for (int i = 0; i < 3; i++) {
                float vv = vl[half * 2 + q][i][k];
                u[q][i] += vv * wu;
                p[q][i] += vv * wv;
            }
    }
    #pragma unroll
    for (int q = 0; q < 2; q++) {
        int n = n0 + half * 2 + q;
        float uv = 0.0f, nn = 0.0f;
        #pragma unroll
        for (int i = 0; i < 3; i++) {
            uv += u[q][i] * p[q][i];
            nn += p[q][i] * p[q][i];
        }
        UV[n * D + j] = uv;
        Vn[n * D + j] = sqrtf(nn);
        #pragma unroll
        for (int i = 0; i < 3; i++) U[(n * 3 + i) * D + j] = u[q][i];
    }
}

// ---------------------------------------------------------------- update MLP + apply
// a = silu(cat(Vn,s) @ w1 + b1) @ w2 + b2 ; s += ass + UV*asv ; v += U*avv
__global__ __launch_bounds__(256) void node_update(
    float* __restrict__ s, float* __restrict__ v,
    const float* __restrict__ Vn, const float* __restrict__ UV, const float* __restrict__ U,
    const float* __restrict__ w1, const float* __restrict__ b1,
    const float* __restrict__ w2, const float* __restrict__ b2)
{
    __shared__ float xl[8][2 * D];
    __shared__ float hl[8][D];
    int j = threadIdx.x & 127;
    int half = threadIdx.x >> 7;
    int n0 = blockIdx.x * 8;
    for (int t = threadIdx.x; t < 8 * 2 * D; t += 256) {
        int r = t >> 8, c = t & 255;
        int n = n0 + r;
        xl[r][c] = (c < D) ? Vn[n * D + c] : s[n * D + c - D];
    }
    __syncthreads();
    float acc[4];
    #pragma unroll
    for (int q = 0; q < 4; q++) acc[q] = b1[j];
    for (int k = 0; k < 2 * D; k++) {
        float w = w1[k * D + j];
        #pragma unroll
        for (int q = 0; q < 4; q++) acc[q] += xl[half * 4 + q][k] * w;
    }
    #pragma unroll
    for (int q = 0; q < 4; q++) hl[half * 4 + q][j] = silu_f(acc[q]);
    __syncthreads();
    float a0[4], a1[4], a2[4];
    #pragma unroll
    for (int q = 0; q < 4; q++) { a0[q] = b2[j]; a1[q] = b2[D + j]; a2[q] = b2[2 * D + j]; }
    for (int k = 0; k < D; k++) {
        float wa = w2[k * D3 + j];
        float wb = w2[k * D3 + D + j];
        float wc = w2[k * D3 + 2 * D + j];
        #pragma unroll
        for (int q = 0; q < 4; q++) {
            float h = hl[half * 4 + q][k];
            a0[q] += h * wa; a1[q] += h * wb; a2[q] += h * wc;
        }
    }
    #pragma unroll
    for (int q = 0; q < 4; q++) {
        int n = n0 + half * 4 + q;
        float sv  = xl[half * 4 + q][D + j];
        float avv = a0[q], asv = a1[q], ass = a2[q];
        s[n * D + j] = sv + ass + UV[n * D + j] * asv;
        #pragma unroll
        for (int i = 0; i < 3; i++) {
            int idx = (n * 3 + i) * D + j;
            v[idx] += U[idx] * avv;
        }
    }
}

// ---------------------------------------------------------------- graph segment sum
__global__ __launch_bounds__(128) void graph_sum(
    const float* __restrict__ s, const int* __restrict__ gi, float* __restrict__ g)
{
    int d = threadIdx.x;
    int n0 = blockIdx.x * 64;
    int n1 = n0 + 64; if (n1 > NN) n1 = NN;
    if (n0 >= NN) return;
    int cur = gi[n0];
    float acc = 0.0f;
    for (int n = n0; n < n1; n++) {
        int gn = gi[n];
        if (gn != cur) { atomicAdd(&g[cur * D + d], acc); acc = 0.0f; cur = gn; }
        acc += s[n * D + d];
    }
    atomicAdd(&g[cur * D + d], acc);
}

// ---------------------------------------------------------------- readout
__global__ __launch_bounds__(128) void out_mlp(
    const float* __restrict__ g,
    const float* __restrict__ w1, const float* __restrict__ b1,
    const float* __restrict__ w2, const float* __restrict__ b2,
    float* __restrict__ out)
{
    __shared__ float gl[D];
    __shared__ float red[2];
    int j = threadIdx.x;
    int gr = blockIdx.x;
    gl[j] = g[gr * D + j];
    __syncthreads();
    float acc = b1[j];
    for (int k = 0; k < D; k++) acc += gl[k] * w1[k * D + j];
    float h = silu_f(acc) * w2[j];
    #pragma unroll
    for (int off = 32; off >= 1; off >>= 1) h += __shfl_down(h, off);
    if ((j & 63) == 0) red[j >> 6] = h;
    __syncthreads();
    if (j == 0) out[gr] = red[0] + red[1] + b2[0];
}

// ================================================================ launch
extern "C" void kernel_launch(void* const* d_in, const int* in_sizes, int n_in,
                              void* d_out, int out_size, void* d_ws, size_t ws_size,
                              hipStream_t stream)
{
    const int*   edge_src   = (const int*)  d_in[0];
    const int*   edge_dst   = (const int*)  d_in[1];
    const float* edge_vec   = (const float*)d_in[2];
    const int*   atom_types = (const int*)  d_in[3];
    const int*   node_gi    = (const int*)  d_in[4];
    const float* embedding  = (const float*)d_in[5];
    const float* phi_w1     = (const float*)d_in[6];
    const float* phi_b1     = (const float*)d_in[7];
    const float* phi_w2     = (const float*)d_in[8];
    const float* phi_b2     = (const float*)d_in[9];
    const float* filt_w     = (const float*)d_in[10];
    const float* filt_b     = (const float*)d_in[11];
    const float* upd_w1     = (const float*)d_in[12];
    const float* upd_b1     = (const float*)d_in[13];
    const float* upd_w2     = (const float*)d_in[14];
    const float* upd_b2     = (const float*)d_in[15];
    const float* U_w        = (const float*)d_in[16];
    const float* V_w        = (const float*)d_in[17];
    const float* out_w1     = (const float*)d_in[18];
    const float* out_b1     = (const float*)d_in[19];
    const float* out_w2     = (const float*)d_in[20];
    const float* out_b2     = (const float*)d_in[21];

    float* ws = (float*)d_ws;
    size_t o = 0;
    float* s_a   = ws + o; o += (size_t)NN * D;
    float* s_b   = ws + o; o += (size_t)NN * D;
    float* v_a   = ws + o; o += (size_t)NN * 3 * D;
    float* v_b   = ws + o; o += (size_t)NN * 3 * D;
    float* phiU  = ws + o; o += (size_t)NN * D3;      // aliased: phi (edge phase) then U (update phase)
    float* UVb   = ws + o; o += (size_t)NN * D;
    float* Vnb   = ws + o; o += (size_t)NN * D;
    float* rbfs  = ws + o; o += (size_t)NE * NRBF;
    float* fcutb = ws + o; o += (size_t)NE;
    float* dirsb = ws + o; o += (size_t)NE * 3;
    float* g     = ws + o; o += (size_t)NG * D;

    init_all<<<NN * D / 256, 256, 0, stream>>>(atom_types, embedding, s_a, v_a, g);
    edge_geom<<<(NE + 255) / 256, 256, 0, stream>>>(edge_vec, rbfs, fcutb, dirsb);

    float *s_cur = s_a, *v_cur = v_a, *s_nxt = s_b, *v_nxt = v_b;
    for (int round = 0; round < 2; round++) {
        phi_mlp<<<NN / 8, 256, 0, stream>>>(s_cur, phi_w1, phi_b1, phi_w2, phi_b2, phiU);
        copy_sv<<<NN * D / 4 / 256, 256, 0, stream>>>(
            (const float4*)s_cur, (float4*)s_nxt, (const float4*)v_cur, (float4*)v_nxt);
        edge_msg<<<NE / 4, 256, 0, stream>>>(edge_src, edge_dst, phiU, v_cur,
                                             rbfs, fcutb, dirsb, filt_w, filt_b,
                                             s_nxt, v_nxt);
        node_uv<<<NN / 4, 256, 0, stream>>>(v_nxt, U_w, V_w, phiU, UVb, Vnb);
        node_update<<<NN / 8, 256, 0, stream>>>(s_nxt, v_nxt, Vnb, UVb, phiU,
                                                upd_w1, upd_b1, upd_w2, upd_b2);
        float* ts = s_cur; s_cur = s_nxt; s_nxt = ts;
        float* tv = v_cur; v_cur = v_nxt; v_nxt = tv;
    }

    graph_sum<<<(NN + 63) / 64, 128, 0, stream>>>(s_cur, node_gi, g);
    out_mlp<<<NG, 128, 0, stream>>>(g, out_w1, out_b1, out_w2, out_b2, (float*)d_out);
}

// Round 2
// 2641.223 us; speedup vs baseline: 1.0296x; 1.0296x over previous
//
#include <hip/hip_runtime.h>

#define NN 20000
#define NE 320000
#define NG 64
#define D 128
#define D3 384
#define NRBF 20
#define PI_F 3.14159265358979323846f
#define RCUT 10.0f

__device__ __forceinline__ float silu_f(float x) {
    return x / (1.0f + __expf(-x));
}

// ---------------------------------------------------------------- init
// s = embedding[atom_types]; v = 0; g = 0; deg = 0
__global__ __launch_bounds__(256) void init_all(
    const int* __restrict__ atype, const float* __restrict__ emb,
    float* __restrict__ s, float* __restrict__ v, float* __restrict__ g,
    int* __restrict__ deg)
{
    int idx = blockIdx.x * blockDim.x + threadIdx.x;
    if (idx < NN * D) {
        int n = idx >> 7, d = idx & 127;
        s[idx] = emb[atype[n] * D + d];
    }
    if (idx < NG * D) g[idx] = 0.0f;
    if (idx < NN) deg[idx] = 0;
    for (int i = idx; i < NN * 3 * D; i += gridDim.x * blockDim.x) v[i] = 0.0f;
}

// ---------------------------------------------------------------- CSR build (by dst)
__global__ __launch_bounds__(256) void csr_count(
    const int* __restrict__ dst, int* __restrict__ deg)
{
    int e = blockIdx.x * blockDim.x + threadIdx.x;
    if (e < NE) atomicAdd(&deg[dst[e]], 1);
}

__global__ __launch_bounds__(1024) void csr_scan(
    const int* __restrict__ deg, int* __restrict__ offs, int* __restrict__ cursor)
{
    __shared__ int part[1024];
    int t = threadIdx.x;
    const int per = (NN + 1023) / 1024;  // 20
    int base = t * per;
    int sum = 0;
    for (int i = 0; i < per; i++) {
        int idx = base + i;
        if (idx < NN) sum += deg[idx];
    }
    part[t] = sum;
    __syncthreads();
    for (int off = 1; off < 1024; off <<= 1) {
        int vv = (t >= off) ? part[t - off] : 0;
        __syncthreads();
        part[t] += vv;
        __syncthreads();
    }
    int run = part[t] - sum;  // exclusive base
    for (int i = 0; i < per; i++) {
        int idx = base + i;
        if (idx < NN) {
            offs[idx] = run;
            cursor[idx] = run;
            run += deg[idx];
        }
    }
    if (t == 1023) offs[NN] = run;  // == NE
}

__global__ __launch_bounds__(256) void csr_scatter(
    const int* __restrict__ dst, int* __restrict__ cursor, int* __restrict__ eid)
{
    int e = blockIdx.x * blockDim.x + threadIdx.x;
    if (e < NE) {
        int p = atomicAdd(&cursor[dst[e]], 1);
        eid[p] = e;
    }
}

// ---------------------------------------------------------------- edge geometry
// rbfs[e][k] = sin((k+1)*pi*r/RCUT)/r * fcut ; fcut[e]; dirs = vec/r
__global__ __launch_bounds__(256) void edge_geom(
    const float* __restrict__ evec,
    float* __restrict__ rbfs, float* __restrict__ fcutb, float* __restrict__ dirs)
{
    int e = blockIdx.x * blockDim.x + threadIdx.x;
    if (e >= NE) return;
    float x = evec[e * 3 + 0], y = evec[e * 3 + 1], z = evec[e * 3 + 2];
    float r = sqrtf(x * x + y * y + z * z);
    float inv = 1.0f / r;
    dirs[e * 3 + 0] = x * inv;
    dirs[e * 3 + 1] = y * inv;
    dirs[e * 3 + 2] = z * inv;
    float f = (r < RCUT) ? 0.5f * (cosf(PI_F * r / RCUT) + 1.0f) : 0.0f;
    fcutb[e] = f;
    float base = PI_F * r / RCUT;
    float sf = inv * f;
    #pragma unroll
    for (int k = 0; k < NRBF; k++) {
        rbfs[e * NRBF + k] = sinf((float)(k + 1) * base) * sf;
    }
}

// ---------------------------------------------------------------- phi MLP (per node)
__global__ __launch_bounds__(256) void phi_mlp(
    const float* __restrict__ s,
    const float* __restrict__ w1, const float* __restrict__ b1,
    const float* __restrict__ w2, const float* __restrict__ b2,
    float* __restrict__ phi)
{
    __shared__ float sl[8][D];
    __shared__ float hl[8][D];
    int j = threadIdx.x & 127;
    int half = threadIdx.x >> 7;
    int n0 = blockIdx.x * 8;
    for (int t = threadIdx.x; t < 8 * D; t += 256)
        sl[t >> 7][t & 127] = s[n0 * D + t];
    __syncthreads();
    float acc[4];
    #pragma unroll
    for (int q = 0; q < 4; q++) acc[q] = b1[j];
    for (int k = 0; k < D; k++) {
        float w = w1[k * D + j];
        #pragma unroll
        for (int q = 0; q < 4; q++) acc[q] += sl[half * 4 + q][k] * w;
    }
    #pragma unroll
    for (int q = 0; q < 4; q++) hl[half * 4 + q][j] = silu_f(acc[q]);
    __syncthreads();
    float a0[4], a1[4], a2[4];
    #pragma unroll
    for (int q = 0; q < 4; q++) { a0[q] = b2[j]; a1[q] = b2[D + j]; a2[q] = b2[2 * D + j]; }
    for (int k = 0; k < D; k++) {
        float wa = w2[k * D3 + j];
        float wb = w2[k * D3 + D + j];
        float wc = w2[k * D3 + 2 * D + j];
        #pragma unroll
        for (int q = 0; q < 4; q++) {
            float h = hl[half * 4 + q][k];
            a0[q] += h * wa; a1[q] += h * wb; a2[q] += h * wc;
        }
    }
    #pragma unroll
    for (int q = 0; q < 4; q++) {
        int n = n0 + half * 4 + q;
        phi[n * D3 + j]         = a0[q];
        phi[n * D3 + D + j]     = a1[q];
        phi[n * D3 + 2 * D + j] = a2[q];
    }
}

// ---------------------------------------------------------------- node gather (message aggregation)
// One wave per destination node; lane owns channels d=lane*2, d+1.
// s_new[n] = s_old[n] + sum_e m2 ; v_new[n] = v_old[n] + sum_e (v_old[src]*m1 + dir*m3)
__global__ __launch_bounds__(256) void node_gather(
    const int* __restrict__ eid, const int* __restrict__ offs,
    const int* __restrict__ src,
    const float* __restrict__ phi,
    const float* __restrict__ s_old, const float* __restrict__ v_old,
    const float* __restrict__ rbfs, const float* __restrict__ fcutb,
    const float* __restrict__ dirs,
    const float* __restrict__ filt_w, const float* __restrict__ filt_b,
    float* __restrict__ s_new, float* __restrict__ v_new)
{
    __shared__ float wlds[NRBF][D3];   // 30720 B
    __shared__ float blds[D3];
    for (int t = threadIdx.x; t < NRBF * D3; t += 256)
        wlds[t / D3][t % D3] = filt_w[t];
    for (int t = threadIdx.x; t < D3; t += 256)
        blds[t] = filt_b[t];
    __syncthreads();

    int wid = blockIdx.x * 4 + (threadIdx.x >> 6);
    if (wid >= NN) return;
    int lane = threadIdx.x & 63;
    int d = lane * 2;
    int e0 = offs[wid], e1 = offs[wid + 1];

    float2 fb0 = *(const float2*)&blds[d];
    float2 fb1 = *(const float2*)&blds[D + d];
    float2 fb2 = *(const float2*)&blds[2 * D + d];

    float sx = 0.f, sy = 0.f;
    float vx[3] = {0.f, 0.f, 0.f}, vy[3] = {0.f, 0.f, 0.f};

    for (int i = e0; i < e1; i += 4) {
        int   et[4]; float fct[4]; float msk[4];
        #pragma unroll
        for (int t = 0; t < 4; t++) {
            bool act = (i + t < e1);
            et[t]  = eid[act ? i + t : e0];
            msk[t] = act ? 1.0f : 0.0f;
            fct[t] = fcutb[et[t]];
        }
        float W0x[4], W0y[4], W1x[4], W1y[4], W2x[4], W2y[4];
        #pragma unroll
        for (int t = 0; t < 4; t++) {
            W0x[t] = fct[t] * fb0.x; W0y[t] = fct[t] * fb0.y;
            W1x[t] = fct[t] * fb1.x; W1y[t] = fct[t] * fb1.y;
            W2x[t] = fct[t] * fb2.x; W2y[t] = fct[t] * fb2.y;
        }
        for (int k = 0; k < NRBF; k++) {
            float2 w0 = *(const float2*)&wlds[k][d];
            float2 w1 = *(const float2*)&wlds[k][D + d];
            float2 w2 = *(const float2*)&wlds[k][2 * D + d];
            #pragma unroll
            for (int t = 0; t < 4; t++) {
                float rb = rbfs[et[t] * NRBF + k];
                W0x[t] += rb * w0.x; W0y[t] += rb * w0.y;
                W1x[t] += rb * w1.x; W1y[t] += rb * w1.y;
                W2x[t] += rb * w2.x; W2y[t] += rb * w2.y;
            }
        }
        #pragma unroll
        for (int t = 0; t < 4; t++) {
            float m = msk[t];
            W0x[t] *= m; W0y[t] *= m;
            W1x[t] *= m; W1y[t] *= m;
            W2x[t] *= m; W2y[t] *= m;
        }
        #pragma unroll
        for (int t = 0; t < 4; t++) {
            int e = et[t];
            int sn = src[e];
            float2 p0 = *(const float2*)&phi[sn * D3 + d];
            float2 p1 = *(const float2*)&phi[sn * D3 + D + d];
            float2 p2 = *(const float2*)&phi[sn * D3 + 2 * D + d];
            float m1x = p0.x * W0x[t], m1y = p0.y * W0y[t];
            float m2x = p1.x * W1x[t], m2y = p1.y * W1y[t];
            float m3x = p2.x * W2x[t], m3y = p2.y * W2y[t];
            sx += m2x; sy += m2y;
            float d0 = dirs[e * 3 + 0], d1 = dirs[e * 3 + 1], d2 = dirs[e * 3 + 2];
            float dir[3] = {d0, d1, d2};
            #pragma unroll
            for (int a = 0; a < 3; a++) {
                float2 vv = *(const float2*)&v_old[(sn * 3 + a) * D + d];
                vx[a] += vv.x * m1x + dir[a] * m3x;
                vy[a] += vv.y * m1y + dir[a] * m3y;
            }
        }
    }

    float2 so = *(const float2*)&s_old[wid * D + d];
    float2 os; os.x = so.x + sx; os.y = so.y + sy;
    *(float2*)&s_new[wid * D + d] = os;
    #pragma unroll
    for (int a = 0; a < 3; a++) {
        float2 vo = *(const float2*)&v_old[(wid * 3 + a) * D + d];
        float2 ov; ov.x = vo.x + vx[a]; ov.y = vo.y + vy[a];
        *(float2*)&v_new[(wid * 3 + a) * D + d] = ov;
    }
}

// ---------------------------------------------------------------- U/Vp/UV/Vn (per node)
__global__ __launch_bounds__(256) void node_uv(
    const float* __restrict__ v,
    const float* __restrict__ Uw, const float* __restrict__ Vw,
    float* __restrict__ U, float* __restrict__ UV, float* __restrict__ Vn)
{
    __shared__ float vl[4][3][D];
    int j = threadIdx.x & 127;
    int half = threadIdx.x >> 7;
    int n0 = blockIdx.x * 4;
    for (int t = threadIdx.x; t < 4 * 3 * D; t += 256)
        vl[t / 384][(t / 128) % 3][t & 127] = v[n0 * 384 + t];
    __syncthreads();
    float u[2][3] = {{0,0,0},{0,0,0}};
    float p[2][3] = {{0,0,0},{0,0,0}};
    for (int k = 0; k < D; k++) {
        float wu = Uw[k * D + j], wv = Vw[k * D + j];
        #pragma unroll
        for (int q = 0; q < 2; q++)
            #pragma unroll
            for (int i = 0; i < 3; i++) {
                float vv = vl[half * 2 + q][i][k];
                u[q][i] += vv * wu;
                p[q][i] += vv * wv;
            }
    }
    #pragma unroll
    for (int q = 0; q < 2; q++) {
        int n = n0 + half * 2 + q;
        float uv = 0.0f, nn = 0.0f;
        #pragma unroll
        for (int i = 0; i < 3; i++) {
            uv += u[q][i] * p[q][i];
            nn += p[q][i] * p[q][i];
        }
        UV[n * D + j] = uv;
        Vn[n * D + j] = sqrtf(nn);
        #pragma unroll
        for (int i = 0; i < 3; i++) U[(n * 3 + i) * D + j] = u[q][i];
    }
}

// ---------------------------------------------------------------- update MLP + apply
__global__ __launch_bounds__(256) void node_update(
    float* __restrict__ s, float* __restrict__ v,
    const float* __restrict__ Vn, const float* __restrict__ UV, const float* __restrict__ U,
    const float* __restrict__ w1, const float* __restrict__ b1,
    const float* __restrict__ w2, const float* __restrict__ b2)
{
    __shared__ float xl[8][2 * D];
    __shared__ float hl[8][D];
    int j = threadIdx.x & 127;
    int half = threadIdx.x >> 7;
    int n0 = blockIdx.x * 8;
    for (int t = threadIdx.x; t < 8 * 2 * D; t += 256) {
        int r = t >> 8, c = t & 255;
        int n = n0 + r;
        xl[r][c] = (c < D) ? Vn[n * D + c] : s[n * D + c - D];
    }
    __syncthreads();
    float acc[4];
    #pragma unroll
    for (int q = 0; q < 4; q++) acc[q] = b1[j];
    for (int k = 0; k < 2 * D; k++) {
        float w = w1[k * D + j];
        #pragma unroll
        for (int q = 0; q < 4; q++) acc[q] += xl[half * 4 + q][k] * w;
    }
    #pragma unroll
    for (int q = 0; q < 4; q++) hl[half * 4 + q][j] = silu_f(acc[q]);
    __syncthreads();
    float a0[4], a1[4], a2[4];
    #pragma unroll
    for (int q = 0; q < 4; q++) { a0[q] = b2[j]; a1[q] = b2[D + j]; a2[q] = b2[2 * D + j]; }
    for (int k = 0; k < D; k++) {
        float wa = w2[k * D3 + j];
        float wb = w2[k * D3 + D + j];
        float wc = w2[k * D3 + 2 * D + j];
        #pragma unroll
        for (int q = 0; q < 4; q++) {
            float h = hl[half * 4 + q][k];
            a0[q] += h * wa; a1[q] += h * wb; a2[q] += h * wc;
        }
    }
    #pragma unroll
    for (int q = 0; q < 4; q++) {
        int n = n0 + half * 4 + q;
        float sv  = xl[half * 4 + q][D + j];
        float avv = a0[q], asv = a1[q], ass = a2[q];
        s[n * D + j] = sv + ass + UV[n * D + j] * asv;
        #pragma unroll
        for (int i = 0; i < 3; i++) {
            int idx = (n * 3 + i) * D + j;
            v[idx] += U[idx] * avv;
        }
    }
}

// ---------------------------------------------------------------- graph segment sum
__global__ __launch_bounds__(128) void graph_sum(
    const float* __restrict__ s, const int* __restrict__ gi, float* __restrict__ g)
{
    int d = threadIdx.x;
    int n0 = blockIdx.x * 64;
    int n1 = n0 + 64; if (n1 > NN) n1 = NN;
    if (n0 >= NN) return;
    int cur = gi[n0];
    float acc = 0.0f;
    for (int n = n0; n < n1; n++) {
        int gn = gi[n];
        if (gn != cur) { atomicAdd(&g[cur * D + d], acc); acc = 0.0f; cur = gn; }
        acc += s[n * D + d];
    }
    atomicAdd(&g[cur * D + d], acc);
}

// ---------------------------------------------------------------- readout
__global__ __launch_bounds__(128) void out_mlp(
    const float* __restrict__ g,
    const float* __restrict__ w1, const float* __restrict__ b1,
    const float* __restrict__ w2, const float* __restrict__ b2,
    float* __restrict__ out)
{
    __shared__ float gl[D];
    __shared__ float red[2];
    int j = threadIdx.x;
    int gr = blockIdx.x;
    gl[j] = g[gr * D + j];
    __syncthreads();
    float acc = b1[j];
    for (int k = 0; k < D; k++) acc += gl[k] * w1[k * D + j];
    float h = silu_f(acc) * w2[j];
    #pragma unroll
    for (int off = 32; off >= 1; off >>= 1) h += __shfl_down(h, off);
    if ((j & 63) == 0) red[j >> 6] = h;
    __syncthreads();
    if (j == 0) out[gr] = red[0] + red[1] + b2[0];
}

// ================================================================ launch
extern "C" void kernel_launch(void* const* d_in, const int* in_sizes, int n_in,
                              void* d_out, int out_size, void* d_ws, size_t ws_size,
                              hipStream_t stream)
{
    const int*   edge_src   = (const int*)  d_in[0];
    const int*   edge_dst   = (const int*)  d_in[1];
    const float* edge_vec   = (const float*)d_in[2];
    const int*   atom_types = (const int*)  d_in[3];
    const int*   node_gi    = (const int*)  d_in[4];
    const float* embedding  = (const float*)d_in[5];
    const float* phi_w1     = (const float*)d_in[6];
    const float* phi_b1     = (const float*)d_in[7];
    const float* phi_w2     = (const float*)d_in[8];
    const float* phi_b2     = (const float*)d_in[9];
    const float* filt_w     = (const float*)d_in[10];
    const float* filt_b     = (const float*)d_in[11];
    const float* upd_w1     = (const float*)d_in[12];
    const float* upd_b1     = (const float*)d_in[13];
    const float* upd_w2     = (const float*)d_in[14];
    const float* upd_b2     = (const float*)d_in[15];
    const float* U_w        = (const float*)d_in[16];
    const float* V_w        = (const float*)d_in[17];
    const float* out_w1     = (const float*)d_in[18];
    const float* out_b1     = (const float*)d_in[19];
    const float* out_w2     = (const float*)d_in[20];
    const float* out_b2     = (const float*)d_in[21];

    float* ws = (float*)d_ws;
    size_t o = 0;
    float* s_a   = ws + o; o += (size_t)NN * D;
    float* s_b   = ws + o; o += (size_t)NN * D;
    float* v_a   = ws + o; o += (size_t)NN * 3 * D;
    float* v_b   = ws + o; o += (size_t)NN * 3 * D;
    float* phiU  = ws + o; o += (size_t)NN * D3;      // phi (edge phase) then U (update phase)
    float* UVb   = ws + o; o += (size_t)NN * D;
    float* Vnb   = ws + o; o += (size_t)NN * D;
    float* rbfs  = ws + o; o += (size_t)NE * NRBF;
    float* fcutb = ws + o; o += (size_t)NE;
    float* dirsb = ws + o; o += (size_t)NE * 3;
    float* g     = ws + o; o += (size_t)NG * D;
    int* deg     = (int*)(ws + o); o += NN;
    int* offs    = (int*)(ws + o); o += NN + 1;
    int* cursor  = (int*)(ws + o); o += NN;
    int* eidb    = (int*)(ws + o); o += NE;

    init_all<<<NN * D / 256, 256, 0, stream>>>(atom_types, embedding, s_a, v_a, g, deg);
    csr_count<<<(NE + 255) / 256, 256, 0, stream>>>(edge_dst, deg);
    csr_scan<<<1, 1024, 0, stream>>>(deg, offs, cursor);
    csr_scatter<<<(NE + 255) / 256, 256, 0, stream>>>(edge_dst, cursor, eidb);
    edge_geom<<<(NE + 255) / 256, 256, 0, stream>>>(edge_vec, rbfs, fcutb, dirsb);

    float *s_cur = s_a, *v_cur = v_a, *s_nxt = s_b, *v_nxt = v_b;
    for (int round = 0; round < 2; round++) {
        phi_mlp<<<NN / 8, 256, 0, stream>>>(s_cur, phi_w1, phi_b1, phi_w2, phi_b2, phiU);
        node_gather<<<NN / 4, 256, 0, stream>>>(eidb, offs, edge_src, phiU, s_cur, v_cur,
                                                rbfs, fcutb, dirsb, filt_w, filt_b,
                                                s_nxt, v_nxt);
        node_uv<<<NN / 4, 256, 0, stream>>>(v_nxt, U_w, V_w, phiU, UVb, Vnb);
        node_update<<<NN / 8, 256, 0, stream>>>(s_nxt, v_nxt, Vnb, UVb, phiU,
                                                upd_w1, upd_b1, upd_w2, upd_b2);
        float* ts = s_cur; s_cur = s_nxt; s_nxt = ts;
        float* tv = v_cur; v_cur = v_nxt; v_nxt = tv;
    }

    graph_sum<<<(NN + 63) / 64, 128, 0, stream>>>(s_cur, node_gi, g);
    out_mlp<<<NG, 128, 0, stream>>>(g, out_w1, out_b1, out_w2, out_b2, (float*)d_out);
}

// Round 3
// 1501.342 us; speedup vs baseline: 1.8112x; 1.7592x over previous
//
#include <hip/hip_runtime.h>

#define NN 20000
#define NE 320000
#define NG 64
#define D 128
#define D3 384
#define NRBF 20
#define PI_F 3.14159265358979323846f
#define RCUT 10.0f

__device__ __forceinline__ float silu_f(float x) {
    return x / (1.0f + __expf(-x));
}

// ---------------------------------------------------------------- init
__global__ __launch_bounds__(256) void init_all(
    const int* __restrict__ atype, const float* __restrict__ emb,
    float* __restrict__ s, float* __restrict__ v, float* __restrict__ g,
    int* __restrict__ deg)
{
    int idx = blockIdx.x * blockDim.x + threadIdx.x;
    if (idx < NN * D) {
        int n = idx >> 7, d = idx & 127;
        s[idx] = emb[atype[n] * D + d];
    }
    if (idx < NG * D) g[idx] = 0.0f;
    if (idx < NN) deg[idx] = 0;
    for (int i = idx; i < NN * 3 * D; i += gridDim.x * blockDim.x) v[i] = 0.0f;
}

// ---------------------------------------------------------------- CSR build (by dst)
__global__ __launch_bounds__(256) void csr_count(
    const int* __restrict__ dst, int* __restrict__ deg)
{
    int e = blockIdx.x * blockDim.x + threadIdx.x;
    if (e < NE) atomicAdd(&deg[dst[e]], 1);
}

__global__ __launch_bounds__(1024) void csr_scan(
    const int* __restrict__ deg, int* __restrict__ offs, int* __restrict__ cursor)
{
    __shared__ int part[1024];
    int t = threadIdx.x;
    const int per = (NN + 1023) / 1024;  // 20
    int base = t * per;
    int sum = 0;
    for (int i = 0; i < per; i++) {
        int idx = base + i;
        if (idx < NN) sum += deg[idx];
    }
    part[t] = sum;
    __syncthreads();
    for (int off = 1; off < 1024; off <<= 1) {
        int vv = (t >= off) ? part[t - off] : 0;
        __syncthreads();
        part[t] += vv;
        __syncthreads();
    }
    int run = part[t] - sum;  // exclusive base
    for (int i = 0; i < per; i++) {
        int idx = base + i;
        if (idx < NN) {
            offs[idx] = run;
            cursor[idx] = run;
            run += deg[idx];
        }
    }
    if (t == 1023) offs[NN] = run;  // == NE
}

__global__ __launch_bounds__(256) void csr_scatter(
    const int* __restrict__ dst, int* __restrict__ cursor, int* __restrict__ eid)
{
    int e = blockIdx.x * blockDim.x + threadIdx.x;
    if (e < NE) {
        int p = atomicAdd(&cursor[dst[e]], 1);
        eid[p] = e;
    }
}

// ---------------------------------------------------------------- edge geometry
// rbfs[e][k] = sin((k+1)*pi*r/RCUT)/r * fcut ; geo[e] = {dir.xyz, fcut}
__global__ __launch_bounds__(256) void edge_geom(
    const float* __restrict__ evec,
    float* __restrict__ rbfs, float4* __restrict__ geo)
{
    int e = blockIdx.x * blockDim.x + threadIdx.x;
    if (e >= NE) return;
    float x = evec[e * 3 + 0], y = evec[e * 3 + 1], z = evec[e * 3 + 2];
    float r = sqrtf(x * x + y * y + z * z);
    float inv = 1.0f / r;
    float f = (r < RCUT) ? 0.5f * (cosf(PI_F * r / RCUT) + 1.0f) : 0.0f;
    float4 g;
    g.x = x * inv; g.y = y * inv; g.z = z * inv; g.w = f;
    geo[e] = g;
    float base = PI_F * r / RCUT;
    float sf = inv * f;
    #pragma unroll
    for (int k = 0; k < NRBF; k++) {
        rbfs[e * NRBF + k] = sinf((float)(k + 1) * base) * sf;
    }
}

// ---------------------------------------------------------------- phi MLP (per node)
__global__ __launch_bounds__(256) void phi_mlp(
    const float* __restrict__ s,
    const float* __restrict__ w1, const float* __restrict__ b1,
    const float* __restrict__ w2, const float* __restrict__ b2,
    float* __restrict__ phi)
{
    __shared__ float sl[8][D];
    __shared__ float hl[8][D];
    int j = threadIdx.x & 127;
    int half = threadIdx.x >> 7;
    int n0 = blockIdx.x * 8;
    for (int t = threadIdx.x; t < 8 * D; t += 256)
        sl[t >> 7][t & 127] = s[n0 * D + t];
    __syncthreads();
    float acc[4];
    #pragma unroll
    for (int q = 0; q < 4; q++) acc[q] = b1[j];
    for (int k = 0; k < D; k++) {
        float w = w1[k * D + j];
        #pragma unroll
        for (int q = 0; q < 4; q++) acc[q] += sl[half * 4 + q][k] * w;
    }
    #pragma unroll
    for (int q = 0; q < 4; q++) hl[half * 4 + q][j] = silu_f(acc[q]);
    __syncthreads();
    float a0[4], a1[4], a2[4];
    #pragma unroll
    for (int q = 0; q < 4; q++) { a0[q] = b2[j]; a1[q] = b2[D + j]; a2[q] = b2[2 * D + j]; }
    for (int k = 0; k < D; k++) {
        float wa = w2[k * D3 + j];
        float wb = w2[k * D3 + D + j];
        float wc = w2[k * D3 + 2 * D + j];
        #pragma unroll
        for (int q = 0; q < 4; q++) {
            float h = hl[half * 4 + q][k];
            a0[q] += h * wa; a1[q] += h * wb; a2[q] += h * wc;
        }
    }
    #pragma unroll
    for (int q = 0; q < 4; q++) {
        int n = n0 + half * 4 + q;
        phi[n * D3 + j]         = a0[q];
        phi[n * D3 + D + j]     = a1[q];
        phi[n * D3 + 2 * D + j] = a2[q];
    }
}

// ---------------------------------------------------------------- node gather
// 512 threads = 8 waves = 4 nodes x 2 channel-halves.
// Wave (node, half): lane owns channel d = half*64 + lane (scalar).
// s_new[n] = s_old[n] + sum_e m2 ; v_new[n] = v_old[n] + sum_e (v_old[src]*m1 + dir*m3)
__global__ __launch_bounds__(512, 4) void node_gather(
    const int* __restrict__ eid, const int* __restrict__ offs,
    const int* __restrict__ src,
    const float* __restrict__ phi,
    const float* __restrict__ s_old, const float* __restrict__ v_old,
    const float* __restrict__ rbfs, const float4* __restrict__ geo,
    const float* __restrict__ filt_w, const float* __restrict__ filt_b,
    float* __restrict__ s_new, float* __restrict__ v_new)
{
    __shared__ float wlds[NRBF][D3];   // 30720 B
    for (int t = threadIdx.x; t < NRBF * D3; t += 512)
        wlds[t / D3][t % D3] = filt_w[t];
    __syncthreads();

    int wave = threadIdx.x >> 6;
    int lane = threadIdx.x & 63;
    int node = blockIdx.x * 4 + (wave >> 1);
    if (node >= NN) return;
    int half = wave & 1;
    int d = half * 64 + lane;

    float fb0 = filt_b[d], fb1 = filt_b[D + d], fb2 = filt_b[2 * D + d];
    int e0 = offs[node], e1 = offs[node + 1];

    float acc_s = 0.f, av0 = 0.f, av1 = 0.f, av2 = 0.f;

    for (int i = e0; i < e1; i += 2) {
        int ib = (i + 1 < e1) ? i + 1 : i;
        float mb = (i + 1 < e1) ? 1.0f : 0.0f;
        int ea = eid[i], eb = eid[ib];
        int sa = src[ea], sb = src[eb];
        float4 ga = geo[ea], gb = geo[eb];
        const float* pra = rbfs + (size_t)ea * NRBF;
        const float* prb = rbfs + (size_t)eb * NRBF;
        const float* ppa = phi + (size_t)sa * D3 + d;
        const float* ppb = phi + (size_t)sb * D3 + d;
        const float* pva = v_old + (size_t)sa * 3 * D + d;
        const float* pvb = v_old + (size_t)sb * 3 * D + d;
        float pa0 = ppa[0], pa1 = ppa[D], pa2 = ppa[2 * D];
        float pb0 = ppb[0], pb1 = ppb[D], pb2 = ppb[2 * D];
        float va0 = pva[0], va1 = pva[D], va2 = pva[2 * D];
        float vb0 = pvb[0], vb1 = pvb[D], vb2 = pvb[2 * D];

        float Wa0 = ga.w * fb0, Wa1 = ga.w * fb1, Wa2 = ga.w * fb2;
        float Wb0 = gb.w * fb0, Wb1 = gb.w * fb1, Wb2 = gb.w * fb2;
        #pragma unroll
        for (int k = 0; k < NRBF; k++) {
            float ra = pra[k], rb = prb[k];
            float w0 = wlds[k][d], w1 = wlds[k][D + d], w2 = wlds[k][2 * D + d];
            Wa0 += ra * w0; Wa1 += ra * w1; Wa2 += ra * w2;
            Wb0 += rb * w0; Wb1 += rb * w1; Wb2 += rb * w2;
        }
        float m1a = pa0 * Wa0, m2a = pa1 * Wa1, m3a = pa2 * Wa2;
        float m1b = pb0 * Wb0 * mb, m2b = pb1 * Wb1 * mb, m3b = pb2 * Wb2 * mb;
        acc_s += m2a + m2b;
        av0 += va0 * m1a + ga.x * m3a + vb0 * m1b + gb.x * m3b;
        av1 += va1 * m1a + ga.y * m3a + vb1 * m1b + gb.y * m3b;
        av2 += va2 * m1a + ga.z * m3a + vb2 * m1b + gb.z * m3b;
    }

    s_new[node * D + d] = s_old[node * D + d] + acc_s;
    v_new[(node * 3 + 0) * D + d] = v_old[(node * 3 + 0) * D + d] + av0;
    v_new[(node * 3 + 1) * D + d] = v_old[(node * 3 + 1) * D + d] + av1;
    v_new[(node * 3 + 2) * D + d] = v_old[(node * 3 + 2) * D + d] + av2;
}

// ---------------------------------------------------------------- U/Vp/UV/Vn (per node)
__global__ __launch_bounds__(256) void node_uv(
    const float* __restrict__ v,
    const float* __restrict__ Uw, const float* __restrict__ Vw,
    float* __restrict__ U, float* __restrict__ UV, float* __restrict__ Vn)
{
    __shared__ float vl[4][3][D];
    int j = threadIdx.x & 127;
    int half = threadIdx.x >> 7;
    int n0 = blockIdx.x * 4;
    for (int t = threadIdx.x; t < 4 * 3 * D; t += 256)
        vl[t / 384][(t / 128) % 3][t & 127] = v[n0 * 384 + t];
    __syncthreads();
    float u[2][3] = {{0,0,0},{0,0,0}};
    float p[2][3] = {{0,0,0},{0,0,0}};
    for (int k = 0; k < D; k++) {
        float wu = Uw[k * D + j], wv = Vw[k * D + j];
        #pragma unroll
        for (int q = 0; q < 2; q++)
            #pragma unroll
            for (int i = 0; i < 3; i++) {
                float vv = vl[half * 2 + q][i][k];
                u[q][i] += vv * wu;
                p[q][i] += vv * wv;
            }
    }
    #pragma unroll
    for (int q = 0; q < 2; q++) {
        int n = n0 + half * 2 + q;
        float uv = 0.0f, nn = 0.0f;
        #pragma unroll
        for (int i = 0; i < 3; i++) {
            uv += u[q][i] * p[q][i];
            nn += p[q][i] * p[q][i];
        }
        UV[n * D + j] = uv;
        Vn[n * D + j] = sqrtf(nn);
        #pragma unroll
        for (int i = 0; i < 3; i++) U[(n * 3 + i) * D + j] = u[q][i];
    }
}

// ---------------------------------------------------------------- update MLP + apply
__global__ __launch_bounds__(256) void node_update(
    float* __restrict__ s, float* __restrict__ v,
    const float* __restrict__ Vn, const float* __restrict__ UV, const float* __restrict__ U,
    const float* __restrict__ w1, const float* __restrict__ b1,
    const float* __restrict__ w2, const float* __restrict__ b2)
{
    __shared__ float xl[8][2 * D];
    __shared__ float hl[8][D];
    int j = threadIdx.x & 127;
    int half = threadIdx.x >> 7;
    int n0 = blockIdx.x * 8;
    for (int t = threadIdx.x; t < 8 * 2 * D; t += 256) {
        int r = t >> 8, c = t & 255;
        int n = n0 + r;
        xl[r][c] = (c < D) ? Vn[n * D + c] : s[n * D + c - D];
    }
    __syncthreads();
    float acc[4];
    #pragma unroll
    for (int q = 0; q < 4; q++) acc[q] = b1[j];
    for (int k = 0; k < 2 * D; k++) {
        float w = w1[k * D + j];
        #pragma unroll
        for (int q = 0; q < 4; q++) acc[q] += xl[half * 4 + q][k] * w;
    }
    #pragma unroll
    for (int q = 0; q < 4; q++) hl[half * 4 + q][j] = silu_f(acc[q]);
    __syncthreads();
    float a0[4], a1[4], a2[4];
    #pragma unroll
    for (int q = 0; q < 4; q++) { a0[q] = b2[j]; a1[q] = b2[D + j]; a2[q] = b2[2 * D + j]; }
    for (int k = 0; k < D; k++) {
        float wa = w2[k * D3 + j];
        float wb = w2[k * D3 + D + j];
        float wc = w2[k * D3 + 2 * D + j];
        #pragma unroll
        for (int q = 0; q < 4; q++) {
            float h = hl[half * 4 + q][k];
            a0[q] += h * wa; a1[q] += h * wb; a2[q] += h * wc;
        }
    }
    #pragma unroll
    for (int q = 0; q < 4; q++) {
        int n = n0 + half * 4 + q;
        float sv  = xl[half * 4 + q][D + j];
        float avv = a0[q], asv = a1[q], ass = a2[q];
        s[n * D + j] = sv + ass + UV[n * D + j] * asv;
        #pragma unroll
        for (int i = 0; i < 3; i++) {
            int idx = (n * 3 + i) * D + j;
            v[idx] += U[idx] * avv;
        }
    }
}

// ---------------------------------------------------------------- graph segment sum
__global__ __launch_bounds__(128) void graph_sum(
    const float* __restrict__ s, const int* __restrict__ gi, float* __restrict__ g)
{
    int d = threadIdx.x;
    int n0 = blockIdx.x * 64;
    int n1 = n0 + 64; if (n1 > NN) n1 = NN;
    if (n0 >= NN) return;
    int cur = gi[n0];
    float acc = 0.0f;
    for (int n = n0; n < n1; n++) {
        int gn = gi[n];
        if (gn != cur) { atomicAdd(&g[cur * D + d], acc); acc = 0.0f; cur = gn; }
        acc += s[n * D + d];
    }
    atomicAdd(&g[cur * D + d], acc);
}

// ---------------------------------------------------------------- readout
__global__ __launch_bounds__(128) void out_mlp(
    const float* __restrict__ g,
    const float* __restrict__ w1, const float* __restrict__ b1,
    const float* __restrict__ w2, const float* __restrict__ b2,
    float* __restrict__ out)
{
    __shared__ float gl[D];
    __shared__ float red[2];
    int j = threadIdx.x;
    int gr = blockIdx.x;
    gl[j] = g[gr * D + j];
    __syncthreads();
    float acc = b1[j];
    for (int k = 0; k < D; k++) acc += gl[k] * w1[k * D + j];
    float h = silu_f(acc) * w2[j];
    #pragma unroll
    for (int off = 32; off >= 1; off >>= 1) h += __shfl_down(h, off);
    if ((j & 63) == 0) red[j >> 6] = h;
    __syncthreads();
    if (j == 0) out[gr] = red[0] + red[1] + b2[0];
}

// ================================================================ launch
extern "C" void kernel_launch(void* const* d_in, const int* in_sizes, int n_in,
                              void* d_out, int out_size, void* d_ws, size_t ws_size,
                              hipStream_t stream)
{
    const int*   edge_src   = (const int*)  d_in[0];
    const int*   edge_dst   = (const int*)  d_in[1];
    const float* edge_vec   = (const float*)d_in[2];
    const int*   atom_types = (const int*)  d_in[3];
    const int*   node_gi    = (const int*)  d_in[4];
    const float* embedding  = (const float*)d_in[5];
    const float* phi_w1     = (const float*)d_in[6];
    const float* phi_b1     = (const float*)d_in[7];
    const float* phi_w2     = (const float*)d_in[8];
    const float* phi_b2     = (const float*)d_in[9];
    const float* filt_w     = (const float*)d_in[10];
    const float* filt_b     = (const float*)d_in[11];
    const float* upd_w1     = (const float*)d_in[12];
    const float* upd_b1     = (const float*)d_in[13];
    const float* upd_w2     = (const float*)d_in[14];
    const float* upd_b2     = (const float*)d_in[15];
    const float* U_w        = (const float*)d_in[16];
    const float* V_w        = (const float*)d_in[17];
    const float* out_w1     = (const float*)d_in[18];
    const float* out_b1     = (const float*)d_in[19];
    const float* out_w2     = (const float*)d_in[20];
    const float* out_b2     = (const float*)d_in[21];

    float* ws = (float*)d_ws;
    size_t o = 0;
    float* s_a   = ws + o; o += (size_t)NN * D;
    float* s_b   = ws + o; o += (size_t)NN * D;
    float* v_a   = ws + o; o += (size_t)NN * 3 * D;
    float* v_b   = ws + o; o += (size_t)NN * 3 * D;
    float* phiU  = ws + o; o += (size_t)NN * D3;      // phi (edge phase) then U (update phase)
    float* UVb   = ws + o; o += (size_t)NN * D;
    float* Vnb   = ws + o; o += (size_t)NN * D;
    float* rbfs  = ws + o; o += (size_t)NE * NRBF;
    float* geo   = ws + o; o += (size_t)NE * 4;
    float* g     = ws + o; o += (size_t)NG * D;
    int* deg     = (int*)(ws + o); o += NN;
    int* offs    = (int*)(ws + o); o += NN + 1;
    int* cursor  = (int*)(ws + o); o += NN;
    int* eidb    = (int*)(ws + o); o += NE;

    init_all<<<NN * D / 256, 256, 0, stream>>>(atom_types, embedding, s_a, v_a, g, deg);
    csr_count<<<(NE + 255) / 256, 256, 0, stream>>>(edge_dst, deg);
    csr_scan<<<1, 1024, 0, stream>>>(deg, offs, cursor);
    csr_scatter<<<(NE + 255) / 256, 256, 0, stream>>>(edge_dst, cursor, eidb);
    edge_geom<<<(NE + 255) / 256, 256, 0, stream>>>(edge_vec, rbfs, (float4*)geo);

    float *s_cur = s_a, *v_cur = v_a, *s_nxt = s_b, *v_nxt = v_b;
    for (int round = 0; round < 2; round++) {
        phi_mlp<<<NN / 8, 256, 0, stream>>>(s_cur, phi_w1, phi_b1, phi_w2, phi_b2, phiU);
        node_gather<<<NN / 4, 512, 0, stream>>>(eidb, offs, edge_src, phiU, s_cur, v_cur,
                                                rbfs, (const float4*)geo, filt_w, filt_b,
                                                s_nxt, v_nxt);
        node_uv<<<NN / 4, 256, 0, stream>>>(v_nxt, U_w, V_w, phiU, UVb, Vnb);
        node_update<<<NN / 8, 256, 0, stream>>>(s_nxt, v_nxt, Vnb, UVb, phiU,
                                                upd_w1, upd_b1, upd_w2, upd_b2);
        float* ts = s_cur; s_cur = s_nxt; s_nxt = ts;
        float* tv = v_cur; v_cur = v_nxt; v_nxt = tv;
    }

    graph_sum<<<(NN + 63) / 64, 128, 0, stream>>>(s_cur, node_gi, g);
    out_mlp<<<NG, 128, 0, stream>>>(g, out_w1, out_b1, out_w2, out_b2, (float*)d_out);
}

// Round 4
// 1293.696 us; speedup vs baseline: 2.1019x; 1.1605x over previous
//
#include <hip/hip_runtime.h>

#define NN 20000
#define NE 320000
#define NG 64
#define D 128
#define D3 384
#define NRBF 20
#define NRBF_PAD 24      // ushorts per rbf row -> 48B, 16B-aligned
#define PI_F 3.14159265358979323846f
#define RCUT 10.0f

typedef unsigned int uint;
typedef unsigned short ushort;

__device__ __forceinline__ float silu_f(float x) {
    return x / (1.0f + __expf(-x));
}
// bf16 (stored as ushort) -> f32
__device__ __forceinline__ float b2f(ushort u) {
    return __uint_as_float(((uint)u) << 16);
}
// f32 -> bf16 RNE
__device__ __forceinline__ ushort f2b(float f) {
    uint u = __float_as_uint(f);
    u = u + 0x7fffu + ((u >> 16) & 1u);
    return (ushort)(u >> 16);
}
// packed-pair extract
__device__ __forceinline__ float plo(uint u) { return __uint_as_float(u << 16); }
__device__ __forceinline__ float phi_(uint u) { return __uint_as_float(u & 0xffff0000u); }

// ---------------------------------------------------------------- init
__global__ __launch_bounds__(256) void init_all(
    const int* __restrict__ atype, const float* __restrict__ emb,
    float* __restrict__ s, float* __restrict__ v, float* __restrict__ g,
    int* __restrict__ deg, uint* __restrict__ vh_u, int* __restrict__ bcount)
{
    int idx = blockIdx.x * blockDim.x + threadIdx.x;
    int stride = gridDim.x * blockDim.x;
    if (idx < NN * D) {
        int n = idx >> 7, d = idx & 127;
        s[idx] = emb[atype[n] * D + d];
    }
    if (idx < NG * D) g[idx] = 0.0f;
    if (idx < NN) deg[idx] = 0;
    if (idx < 64) bcount[idx] = 0;
    for (int i = idx; i < NN * 3 * D; i += stride) v[i] = 0.0f;
    for (int i = idx; i < NN * D3 / 2; i += stride) vh_u[i] = 0u;   // vh = bf16 zeros
}

// ---------------------------------------------------------------- CSR build (by dst)
__global__ __launch_bounds__(256) void csr_count(
    const int* __restrict__ dst, int* __restrict__ deg)
{
    int e = blockIdx.x * blockDim.x + threadIdx.x;
    if (e < NE) atomicAdd(&deg[dst[e]], 1);
}

__global__ __launch_bounds__(1024) void csr_scan(
    const int* __restrict__ deg, int* __restrict__ offs, int* __restrict__ cursor)
{
    __shared__ int part[1024];
    int t = threadIdx.x;
    const int per = (NN + 1023) / 1024;  // 20
    int base = t * per;
    int sum = 0;
    for (int i = 0; i < per; i++) {
        int idx = base + i;
        if (idx < NN) sum += deg[idx];
    }
    part[t] = sum;
    __syncthreads();
    for (int off = 1; off < 1024; off <<= 1) {
        int vv = (t >= off) ? part[t - off] : 0;
        __syncthreads();
        part[t] += vv;
        __syncthreads();
    }
    int run = part[t] - sum;  // exclusive base
    for (int i = 0; i < per; i++) {
        int idx = base + i;
        if (idx < NN) {
            offs[idx] = run;
            cursor[idx] = run;
            run += deg[idx];
        }
    }
    if (t == 1023) offs[NN] = run;  // == NE
}

__global__ __launch_bounds__(256) void csr_scatter(
    const int* __restrict__ dst, int* __restrict__ cursor, int* __restrict__ eid)
{
    int e = blockIdx.x * blockDim.x + threadIdx.x;
    if (e < NE) {
        int p = atomicAdd(&cursor[dst[e]], 1);
        eid[p] = e;
    }
}

// ---------------------------------------------------------------- degree sort (counting)
__global__ __launch_bounds__(256) void dbucket(
    const int* __restrict__ deg, int* __restrict__ bcount)
{
    int n = blockIdx.x * blockDim.x + threadIdx.x;
    if (n < NN) {
        int b = deg[n]; if (b > 63) b = 63;
        atomicAdd(&bcount[b], 1);
    }
}

__global__ void dscan(const int* __restrict__ bcount, int* __restrict__ bpos)
{
    if (threadIdx.x == 0) {
        int run = 0;
        for (int b = 63; b >= 0; b--) { bpos[b] = run; run += bcount[b]; }  // descending degree
    }
}

__global__ __launch_bounds__(256) void dscatter(
    const int* __restrict__ deg, int* __restrict__ bpos, int* __restrict__ perm)
{
    int n = blockIdx.x * blockDim.x + threadIdx.x;
    if (n < NN) {
        int b = deg[n]; if (b > 63) b = 63;
        int p = atomicAdd(&bpos[b], 1);
        perm[p] = n;
    }
}

// ---------------------------------------------------------------- edge geometry
// rbf_h[e][k] = bf16( sin((k+1)*pi*r/RCUT)/r * fcut ) ; geo[e] = {dir.xyz, fcut}
__global__ __launch_bounds__(256) void edge_geom(
    const float* __restrict__ evec,
    ushort* __restrict__ rbf_h, float4* __restrict__ geo)
{
    int e = blockIdx.x * blockDim.x + threadIdx.x;
    if (e >= NE) return;
    float x = evec[e * 3 + 0], y = evec[e * 3 + 1], z = evec[e * 3 + 2];
    float r = sqrtf(x * x + y * y + z * z);
    float inv = 1.0f / r;
    float f = (r < RCUT) ? 0.5f * (cosf(PI_F * r / RCUT) + 1.0f) : 0.0f;
    float4 g;
    g.x = x * inv; g.y = y * inv; g.z = z * inv; g.w = f;
    geo[e] = g;
    float base = PI_F * r / RCUT;
    float sf = inv * f;
    #pragma unroll
    for (int k = 0; k < NRBF; k++) {
        rbf_h[(size_t)e * NRBF_PAD + k] = f2b(sinf((float)(k + 1) * base) * sf);
    }
}

// ---------------------------------------------------------------- phi MLP (per node)
// phi = silu(s @ w1 + b1) @ w2 + b2, stored bf16 [n][seg*128 + j]
__global__ __launch_bounds__(256) void phi_mlp(
    const float* __restrict__ s,
    const float* __restrict__ w1, const float* __restrict__ b1,
    const float* __restrict__ w2, const float* __restrict__ b2,
    ushort* __restrict__ phi_h)
{
    __shared__ float sl[8][D];
    __shared__ float hl[8][D];
    int j = threadIdx.x & 127;
    int half = threadIdx.x >> 7;
    int n0 = blockIdx.x * 8;
    for (int t = threadIdx.x; t < 8 * D; t += 256)
        sl[t >> 7][t & 127] = s[n0 * D + t];
    __syncthreads();
    float acc[4];
    #pragma unroll
    for (int q = 0; q < 4; q++) acc[q] = b1[j];
    for (int k = 0; k < D; k++) {
        float w = w1[k * D + j];
        #pragma unroll
        for (int q = 0; q < 4; q++) acc[q] += sl[half * 4 + q][k] * w;
    }
    #pragma unroll
    for (int q = 0; q < 4; q++) hl[half * 4 + q][j] = silu_f(acc[q]);
    __syncthreads();
    float a0[4], a1[4], a2[4];
    #pragma unroll
    for (int q = 0; q < 4; q++) { a0[q] = b2[j]; a1[q] = b2[D + j]; a2[q] = b2[2 * D + j]; }
    for (int k = 0; k < D; k++) {
        float wa = w2[k * D3 + j];
        float wb = w2[k * D3 + D + j];
        float wc = w2[k * D3 + 2 * D + j];
        #pragma unroll
        for (int q = 0; q < 4; q++) {
            float h = hl[half * 4 + q][k];
            a0[q] += h * wa; a1[q] += h * wb; a2[q] += h * wc;
        }
    }
    #pragma unroll
    for (int q = 0; q < 4; q++) {
        int n = n0 + half * 4 + q;
        phi_h[(size_t)n * D3 + j]         = f2b(a0[q]);
        phi_h[(size_t)n * D3 + D + j]     = f2b(a1[q]);
        phi_h[(size_t)n * D3 + 2 * D + j] = f2b(a2[q]);
    }
}

// ---------------------------------------------------------------- node gather
// 512 threads = 8 waves = 4 nodes x 2 channel-halves; nodes taken via degree-sorted perm.
__global__ __launch_bounds__(512, 4) void node_gather(
    const int* __restrict__ eid, const int* __restrict__ offs,
    const int* __restrict__ perm, const int* __restrict__ src,
    const ushort* __restrict__ phi_h,
    const float* __restrict__ s_old, const float* __restrict__ v_old,
    const ushort* __restrict__ vh,
    const ushort* __restrict__ rbf_h, const float4* __restrict__ geo,
    const float* __restrict__ filt_w, const float* __restrict__ filt_b,
    float* __restrict__ s_new, float* __restrict__ v_new)
{
    __shared__ float wlds[NRBF][D3];   // 30720 B, fp32 exact
    for (int t = threadIdx.x; t < NRBF * D3; t += 512)
        wlds[t / D3][t % D3] = filt_w[t];
    __syncthreads();

    int wave = threadIdx.x >> 6;
    int lane = threadIdx.x & 63;
    int widx = blockIdx.x * 4 + (wave >> 1);
    if (widx >= NN) return;
    int node = perm[widx];
    int half = wave & 1;
    int d = half * 64 + lane;

    float fb0 = filt_b[d], fb1 = filt_b[D + d], fb2 = filt_b[2 * D + d];
    int e0 = offs[node], e1 = offs[node + 1];

    float acc_s = 0.f, av0 = 0.f, av1 = 0.f, av2 = 0.f;

    for (int i = e0; i < e1; i += 2) {
        bool hb = (i + 1 < e1);
        int ea = eid[i], eb = eid[hb ? i + 1 : i];
        float mb = hb ? 1.0f : 0.0f;
        int sa = src[ea], sb = src[eb];
        float4 ga = geo[ea], gb = geo[eb];
        const uint4* rpa = (const uint4*)(rbf_h + (size_t)ea * NRBF_PAD);
        const uint4* rpb = (const uint4*)(rbf_h + (size_t)eb * NRBF_PAD);
        uint4 ra0 = rpa[0], ra1 = rpa[1];
        uint2 ra2 = *(const uint2*)(rpa + 2);
        uint4 rb0 = rpb[0], rb1 = rpb[1];
        uint2 rb2 = *(const uint2*)(rpb + 2);
        const ushort* ppa = phi_h + (size_t)sa * D3 + d;
        const ushort* ppb = phi_h + (size_t)sb * D3 + d;
        const ushort* qva = vh + (size_t)sa * D3 + d;
        const ushort* qvb = vh + (size_t)sb * D3 + d;
        float pa0 = b2f(ppa[0]), pa1 = b2f(ppa[D]), pa2 = b2f(ppa[2 * D]);
        float pb0 = b2f(ppb[0]), pb1 = b2f(ppb[D]), pb2 = b2f(ppb[2 * D]);
        float va0 = b2f(qva[0]), va1 = b2f(qva[D]), va2 = b2f(qva[2 * D]);
        float vb0 = b2f(qvb[0]), vb1 = b2f(qvb[D]), vb2 = b2f(qvb[2 * D]);

        float Wa0 = ga.w * fb0, Wa1 = ga.w * fb1, Wa2 = ga.w * fb2;
        float Wb0 = gb.w * fb0, Wb1 = gb.w * fb1, Wb2 = gb.w * fb2;
        #define RSTEP(k, RA, RB) { \
            float ra_ = RA, rb_ = RB; \
            float w0 = wlds[k][d], w1 = wlds[k][D + d], w2 = wlds[k][2 * D + d]; \
            Wa0 += ra_ * w0; Wa1 += ra_ * w1; Wa2 += ra_ * w2; \
            Wb0 += rb_ * w0; Wb1 += rb_ * w1; Wb2 += rb_ * w2; }
        RSTEP(0,  plo(ra0.x), plo(rb0.x))  RSTEP(1,  phi_(ra0.x), phi_(rb0.x))
        RSTEP(2,  plo(ra0.y), plo(rb0.y))  RSTEP(3,  phi_(ra0.y), phi_(rb0.y))
        RSTEP(4,  plo(ra0.z), plo(rb0.z))  RSTEP(5,  phi_(ra0.z), phi_(rb0.z))
        RSTEP(6,  plo(ra0.w), plo(rb0.w))  RSTEP(7,  phi_(ra0.w), phi_(rb0.w))
        RSTEP(8,  plo(ra1.x), plo(rb1.x))  RSTEP(9,  phi_(ra1.x), phi_(rb1.x))
        RSTEP(10, plo(ra1.y), plo(rb1.y))  RSTEP(11, phi_(ra1.y), phi_(rb1.y))
        RSTEP(12, plo(ra1.z), plo(rb1.z))  RSTEP(13, phi_(ra1.z), phi_(rb1.z))
        RSTEP(14, plo(ra1.w), plo(rb1.w))  RSTEP(15, phi_(ra1.w), phi_(rb1.w))
        RSTEP(16, plo(ra2.x), plo(rb2.x))  RSTEP(17, phi_(ra2.x), phi_(rb2.x))
        RSTEP(18, plo(ra2.y), plo(rb2.y))  RSTEP(19, phi_(ra2.y), phi_(rb2.y))
        #undef RSTEP

        float m1a = pa0 * Wa0, m2a = pa1 * Wa1, m3a = pa2 * Wa2;
        float m1b = pb0 * Wb0 * mb, m2b = pb1 * Wb1 * mb, m3b = pb2 * Wb2 * mb;
        acc_s += m2a + m2b;
        av0 += va0 * m1a + ga.x * m3a + vb0 * m1b + gb.x * m3b;
        av1 += va1 * m1a + ga.y * m3a + vb1 * m1b + gb.y * m3b;
        av2 += va2 * m1a + ga.z * m3a + vb2 * m1b + gb.z * m3b;
    }

    s_new[node * D + d] = s_old[node * D + d] + acc_s;
    v_new[(node * 3 + 0) * D + d] = v_old[(node * 3 + 0) * D + d] + av0;
    v_new[(node * 3 + 1) * D + d] = v_old[(node * 3 + 1) * D + d] + av1;
    v_new[(node * 3 + 2) * D + d] = v_old[(node * 3 + 2) * D + d] + av2;
}

// ---------------------------------------------------------------- U/Vp/UV/Vn (per node)
__global__ __launch_bounds__(256) void node_uv(
    const float* __restrict__ v,
    const float* __restrict__ Uw, const float* __restrict__ Vw,
    float* __restrict__ U, float* __restrict__ UV, float* __restrict__ Vn)
{
    __shared__ float vl[4][3][D];
    int j = threadIdx.x & 127;
    int half = threadIdx.x >> 7;
    int n0 = blockIdx.x * 4;
    for (int t = threadIdx.x; t < 4 * 3 * D; t += 256)
        vl[t / 384][(t / 128) % 3][t & 127] = v[n0 * 384 + t];
    __syncthreads();
    float u[2][3] = {{0,0,0},{0,0,0}};
    float p[2][3] = {{0,0,0},{0,0,0}};
    for (int k = 0; k < D; k++) {
        float wu = Uw[k * D + j], wv = Vw[k * D + j];
        #pragma unroll
        for (int q = 0; q < 2; q++)
            #pragma unroll
            for (int i = 0; i < 3; i++) {
                float vv = vl[half * 2 + q][i][k];
                u[q][i] += vv * wu;
                p[q][i] += vv * wv;
            }
    }
    #pragma unroll
    for (int q = 0; q < 2; q++) {
        int n = n0 + half * 2 + q;
        float uv = 0.0f, nn = 0.0f;
        #pragma unroll
        for (int i = 0; i < 3; i++) {
            uv += u[q][i] * p[q][i];
            nn += p[q][i] * p[q][i];
        }
        UV[n * D + j] = uv;
        Vn[n * D + j] = sqrtf(nn);
        #pragma unroll
        for (int i = 0; i < 3; i++) U[(n * 3 + i) * D + j] = u[q][i];
    }
}

// ---------------------------------------------------------------- update MLP + apply
// also writes bf16 shadow of the final v for next round's gather
__global__ __launch_bounds__(256) void node_update(
    float* __restrict__ s, float* __restrict__ v, ushort* __restrict__ vh,
    const float* __restrict__ Vn, const float* __restrict__ UV, const float* __restrict__ U,
    const float* __restrict__ w1, const float* __restrict__ b1,
    const float* __restrict__ w2, const float* __restrict__ b2)
{
    __shared__ float xl[8][2 * D];
    __shared__ float hl[8][D];
    int j = threadIdx.x & 127;
    int half = threadIdx.x >> 7;
    int n0 = blockIdx.x * 8;
    for (int t = threadIdx.x; t < 8 * 2 * D; t += 256) {
        int r = t >> 8, c = t & 255;
        int n = n0 + r;
        xl[r][c] = (c < D) ? Vn[n * D + c] : s[n * D + c - D];
    }
    __syncthreads();
    float acc[4];
    #pragma unroll
    for (int q = 0; q < 4; q++) acc[q] = b1[j];
    for (int k = 0; k < 2 * D; k++) {
        float w = w1[k * D + j];
        #pragma unroll
        for (int q = 0; q < 4; q++) acc[q] += xl[half * 4 + q][k] * w;
    }
    #pragma unroll
    for (int q = 0; q < 4; q++) hl[half * 4 + q][j] = silu_f(acc[q]);
    __syncthreads();
    float a0[4], a1[4], a2[4];
    #pragma unroll
    for (int q = 0; q < 4; q++) { a0[q] = b2[j]; a1[q] = b2[D + j]; a2[q] = b2[2 * D + j]; }
    for (int k = 0; k < D; k++) {
        float wa = w2[k * D3 + j];
        float wb = w2[k * D3 + D + j];
        float wc = w2[k * D3 + 2 * D + j];
        #pragma unroll
        for (int q = 0; q < 4; q++) {
            float h = hl[half * 4 + q][k];
            a0[q] += h * wa; a1[q] += h * wb; a2[q] += h * wc;
        }
    }
    #pragma unroll
    for (int q = 0; q < 4; q++) {
        int n = n0 + half * 4 + q;
        float sv  = xl[half * 4 + q][D + j];
        float avv = a0[q], asv = a1[q], ass = a2[q];
        s[n * D + j] = sv + ass + UV[n * D + j] * asv;
        #pragma unroll
        for (int i = 0; i < 3; i++) {
            int idx = (n * 3 + i) * D + j;
            float vf = v[idx] + U[idx] * avv;
            v[idx] = vf;
            vh[idx] = f2b(vf);
        }
    }
}

// ---------------------------------------------------------------- graph segment sum
__global__ __launch_bounds__(128) void graph_sum(
    const float* __restrict__ s, const int* __restrict__ gi, float* __restrict__ g)
{
    int d = threadIdx.x;
    int n0 = blockIdx.x * 64;
    int n1 = n0 + 64; if (n1 > NN) n1 = NN;
    if (n0 >= NN) return;
    int cur = gi[n0];
    float acc = 0.0f;
    for (int n = n0; n < n1; n++) {
        int gn = gi[n];
        if (gn != cur) { atomicAdd(&g[cur * D + d], acc); acc = 0.0f; cur = gn; }
        acc += s[n * D + d];
    }
    atomicAdd(&g[cur * D + d], acc);
}

// ---------------------------------------------------------------- readout
__global__ __launch_bounds__(128) void out_mlp(
    const float* __restrict__ g,
    const float* __restrict__ w1, const float* __restrict__ b1,
    const float* __restrict__ w2, const float* __restrict__ b2,
    float* __restrict__ out)
{
    __shared__ float gl[D];
    __shared__ float red[2];
    int j = threadIdx.x;
    int gr = blockIdx.x;
    gl[j] = g[gr * D + j];
    __syncthreads();
    float acc = b1[j];
    for (int k = 0; k < D; k++) acc += gl[k] * w1[k * D + j];
    float h = silu_f(acc) * w2[j];
    #pragma unroll
    for (int off = 32; off >= 1; off >>= 1) h += __shfl_down(h, off);
    if ((j & 63) == 0) red[j >> 6] = h;
    __syncthreads();
    if (j == 0) out[gr] = red[0] + red[1] + b2[0];
}

// ================================================================ launch
extern "C" void kernel_launch(void* const* d_in, const int* in_sizes, int n_in,
                              void* d_out, int out_size, void* d_ws, size_t ws_size,
                              hipStream_t stream)
{
    const int*   edge_src   = (const int*)  d_in[0];
    const int*   edge_dst   = (const int*)  d_in[1];
    const float* edge_vec   = (const float*)d_in[2];
    const int*   atom_types = (const int*)  d_in[3];
    const int*   node_gi    = (const int*)  d_in[4];
    const float* embedding  = (const float*)d_in[5];
    const float* phi_w1     = (const float*)d_in[6];
    const float* phi_b1     = (const float*)d_in[7];
    const float* phi_w2     = (const float*)d_in[8];
    const float* phi_b2     = (const float*)d_in[9];
    const float* filt_w     = (const float*)d_in[10];
    const float* filt_b     = (const float*)d_in[11];
    const float* upd_w1     = (const float*)d_in[12];
    const float* upd_b1     = (const float*)d_in[13];
    const float* upd_w2     = (const float*)d_in[14];
    const float* upd_b2     = (const float*)d_in[15];
    const float* U_w        = (const float*)d_in[16];
    const float* V_w        = (const float*)d_in[17];
    const float* out_w1     = (const float*)d_in[18];
    const float* out_b1     = (const float*)d_in[19];
    const float* out_w2     = (const float*)d_in[20];
    const float* out_b2     = (const float*)d_in[21];

    float* ws = (float*)d_ws;
    size_t o = 0;
    float* s_a   = ws + o; o += (size_t)NN * D;
    float* s_b   = ws + o; o += (size_t)NN * D;
    float* v_a   = ws + o; o += (size_t)NN * 3 * D;
    float* v_b   = ws + o; o += (size_t)NN * 3 * D;
    float* Ubuf  = ws + o; o += (size_t)NN * D3;      // U (fp32); phi_h (bf16) aliases its start
    float* UVb   = ws + o; o += (size_t)NN * D;
    float* Vnb   = ws + o; o += (size_t)NN * D;
    float* rbf_f = ws + o; o += (size_t)NE * NRBF_PAD / 2;   // bf16 storage
    float* geo   = ws + o; o += (size_t)NE * 4;
    float* vh_f  = ws + o; o += (size_t)NN * D3 / 2;          // bf16 storage
    float* g     = ws + o; o += (size_t)NG * D;
    int* deg     = (int*)(ws + o); o += NN;
    int* offs    = (int*)(ws + o); o += NN + 1;
    int* cursor  = (int*)(ws + o); o += NN;
    int* perm    = (int*)(ws + o); o += NN;
    int* bcount  = (int*)(ws + o); o += 64;
    int* bpos    = (int*)(ws + o); o += 64;
    int* eidb    = (int*)(ws + o); o += NE;

    ushort* phi_h = (ushort*)Ubuf;
    ushort* vh    = (ushort*)vh_f;
    ushort* rbf_h = (ushort*)rbf_f;

    init_all<<<NN * D / 256, 256, 0, stream>>>(atom_types, embedding, s_a, v_a, g,
                                               deg, (uint*)vh_f, bcount);
    csr_count<<<(NE + 255) / 256, 256, 0, stream>>>(edge_dst, deg);
    csr_scan<<<1, 1024, 0, stream>>>(deg, offs, cursor);
    csr_scatter<<<(NE + 255) / 256, 256, 0, stream>>>(edge_dst, cursor, eidb);
    dbucket<<<(NN + 255) / 256, 256, 0, stream>>>(deg, bcount);
    dscan<<<1, 64, 0, stream>>>(bcount, bpos);
    dscatter<<<(NN + 255) / 256, 256, 0, stream>>>(deg, bpos, perm);
    edge_geom<<<(NE + 255) / 256, 256, 0, stream>>>(edge_vec, rbf_h, (float4*)geo);

    float *s_cur = s_a, *v_cur = v_a, *s_nxt = s_b, *v_nxt = v_b;
    for (int round = 0; round < 2; round++) {
        phi_mlp<<<NN / 8, 256, 0, stream>>>(s_cur, phi_w1, phi_b1, phi_w2, phi_b2, phi_h);
        node_gather<<<NN / 4, 512, 0, stream>>>(eidb, offs, perm, edge_src, phi_h,
                                                s_cur, v_cur, vh, rbf_h,
                                                (const float4*)geo, filt_w, filt_b,
                                                s_nxt, v_nxt);
        node_uv<<<NN / 4, 256, 0, stream>>>(v_nxt, U_w, V_w, Ubuf, UVb, Vnb);
        node_update<<<NN / 8, 256, 0, stream>>>(s_nxt, v_nxt, vh, Vnb, UVb, Ubuf,
                                                upd_w1, upd_b1, upd_w2, upd_b2);
        float* ts = s_cur; s_cur = s_nxt; s_nxt = ts;
        float* tv = v_cur; v_cur = v_nxt; v_nxt = tv;
    }

    graph_sum<<<(NN + 63) / 64, 128, 0, stream>>>(s_cur, node_gi, g);
    out_mlp<<<NG, 128, 0, stream>>>(g, out_w1, out_b1, out_w2, out_b2, (float*)d_out);
}